// Round 17
// baseline (464.883 us; speedup 1.0000x reference)
//
#include <hip/hip_runtime.h>
#include <hip/hip_bf16.h>

#define N_NODES 100000
#define N_EDGES 3200000
#define IN_F 128
#define OUT_F 64
#define HEADS 8
#define ALPHA 0.2f

#define BSHIFT 7
#define NBUCK 782           // ceil(100000 / 128)
#define CHUNK 2048          // edges per partition block
#define NPBLK 1563          // ceil(N_EDGES / CHUNK)
#define XADOT_BLKS 1024     // node-work blocks in the fused xadot+bcount kernel

typedef __bf16 bf16x8 __attribute__((ext_vector_type(8)));
typedef float f32x4 __attribute__((ext_vector_type(4)));
typedef __attribute__((ext_vector_type(8))) unsigned short ushort8;

static __device__ __forceinline__ unsigned short f2b(float f) {
    __hip_bfloat16 h = __float2bfloat16(f);
    return __builtin_bit_cast(unsigned short, h);
}

static __device__ __forceinline__ void gll16(const void* g, void* l) {
    __builtin_amdgcn_global_load_lds(
        (const __attribute__((address_space(1))) void*)g,
        (__attribute__((address_space(3))) void*)l, 16, 0, 0);
}

// ------- merged prep: Wt transpose (blocks 0-255), uvT (block 256),
//         bhist zero (block 257) ------------------------------------------
__global__ __launch_bounds__(256) void k_prep(const float* __restrict__ W,
                                              const float* __restrict__ a,
                                              unsigned short* __restrict__ Wt,
                                              float* __restrict__ uvT,
                                              int* __restrict__ bhist) {
    int b = blockIdx.x, t = threadIdx.x;
    if (b < 256) {
        int idx = b * 256 + t;          // c*128 + k
        int k = idx & 127;
        int c = idx >> 7;
        int h = c >> 6;
        int f = c & 63;
        Wt[idx] = f2b(W[h * IN_F * OUT_F + k * OUT_F + f]);
    } else if (b == 256) {
#pragma unroll
        for (int j = 0; j < 4; ++j) {
            int t2 = t + j * 256;       // 0..1023 = h*128+k
            int h = t2 >> 7, k = t2 & 127;
            const float* Wrow = W + h * IN_F * OUT_F + k * OUT_F;
            const float* ah = a + h * 2 * OUT_F;
            float su = 0.f, sv = 0.f;
            for (int f = 0; f < OUT_F; ++f) {
                float wv = Wrow[f];
                su += wv * ah[f];
                sv += wv * ah[OUT_F + f];
            }
            uvT[k * 16 + h] = su;
            uvT[k * 16 + 8 + h] = sv;
        }
    } else {
        for (int i = t; i < NBUCK; i += 256) bhist[i] = 0;
    }
}

// ------- fused: xadot (blocks < XADOT_BLKS) + bucket histogram ------------
__global__ __launch_bounds__(256) void k_xadot(const float* __restrict__ x,
                                               const float* __restrict__ uvT,
                                               const int* __restrict__ src,
                                               unsigned short* __restrict__ xb,
                                               float* __restrict__ asrc,
                                               float* __restrict__ atgt,
                                               int* __restrict__ bhist) {
    const int b = blockIdx.x, t = threadIdx.x;
    if (b >= XADOT_BLKS) {
        __shared__ int h[NBUCK];
        for (int i = t; i < NBUCK; i += 256) h[i] = 0;
        __syncthreads();
        int cb = b - XADOT_BLKS;
        int i0 = cb * CHUNK;
        int iend = i0 + CHUNK;
        if (iend > N_EDGES) iend = N_EDGES;
        for (int i = i0 + t; i < iend; i += 256)
            atomicAdd(&h[src[i] >> BSHIFT], 1);
        __syncthreads();
        for (int i = t; i < NBUCK; i += 256)
            if (h[i]) atomicAdd(&bhist[i], h[i]);
        return;
    }
    const int lane = t & 63, wid = t >> 6;
    const int o = lane & 15, q = lane >> 4;
    float up[32];
#pragma unroll
    for (int j = 0; j < 32; ++j) up[j] = uvT[(q * 32 + j) * 16 + o];

    for (int n = b * 4 + wid; n < N_NODES; n += XADOT_BLKS * 4) {
        const float* xr = x + (size_t)n * 128;
        float2 xv2 = *reinterpret_cast<const float2*>(xr + 2 * lane);
        ushort2 pv = make_ushort2(f2b(xv2.x), f2b(xv2.y));
        *reinterpret_cast<ushort2*>(xb + (size_t)n * 128 + 2 * lane) = pv;
        float r = 0.f;
        const float4* xq = reinterpret_cast<const float4*>(xr + q * 32);
#pragma unroll
        for (int j = 0; j < 8; ++j) {
            float4 xv = xq[j];
            r = fmaf(xv.x, up[4 * j], r);
            r = fmaf(xv.y, up[4 * j + 1], r);
            r = fmaf(xv.z, up[4 * j + 2], r);
            r = fmaf(xv.w, up[4 * j + 3], r);
        }
        r += __shfl_xor(r, 16);
        r += __shfl_xor(r, 32);
        if (lane < 8) asrc[n * 8 + o] = r;
        else if (lane < 16) atgt[n * 8 + (o - 8)] = r;
    }
}

// ---------------- bucket scan (1 block); also init cursors ----------------
__global__ __launch_bounds__(1024) void k_bscan(const int* __restrict__ bhist,
                                                int* __restrict__ bstart,
                                                int* __restrict__ bcursor,
                                                int* __restrict__ rowptr) {
    __shared__ int s[1024];
    int t = threadIdx.x;
    int v = (t < NBUCK) ? bhist[t] : 0;
    s[t] = v;
    __syncthreads();
    for (int d = 1; d < 1024; d <<= 1) {
        int add = (t >= d) ? s[t - d] : 0;
        __syncthreads();
        s[t] += add;
        __syncthreads();
    }
    if (t < NBUCK) {
        int st = s[t] - v;
        bstart[t] = st;
        bcursor[t] = st;
    }
    if (t == 0) {
        bstart[NBUCK] = N_EDGES;
        rowptr[N_NODES] = N_EDGES;
    }
}

// ---------------- pass 1: partition edges into bucket regions -------------
__global__ __launch_bounds__(256) void k_bscatter(const int* __restrict__ src,
                                                  const int* __restrict__ tgt,
                                                  int* __restrict__ bcursor,
                                                  unsigned int* __restrict__ pairs) {
    __shared__ int h[NBUCK];
    __shared__ int rsv[NBUCK];
    for (int i = threadIdx.x; i < NBUCK; i += 256) h[i] = 0;
    __syncthreads();
    int i0 = blockIdx.x * CHUNK;
    int iend = i0 + CHUNK;
    if (iend > N_EDGES) iend = N_EDGES;
    for (int i = i0 + threadIdx.x; i < iend; i += 256)
        atomicAdd(&h[src[i] >> BSHIFT], 1);
    __syncthreads();
    for (int i = threadIdx.x; i < NBUCK; i += 256) {
        int c = h[i];
        rsv[i] = c ? atomicAdd(&bcursor[i], c) : 0;
        h[i] = 0;
    }
    __syncthreads();
    for (int i = i0 + threadIdx.x; i < iend; i += 256) {
        int s = src[i];
        int b = s >> BSHIFT;
        int p = rsv[b] + atomicAdd(&h[b], 1);
        pairs[p] = ((unsigned)(s & 127) << 17) | (unsigned)tgt[i];
    }
}

// ---------------- pass 2: in-bucket counting sort -> stgt + rowptr --------
__global__ __launch_bounds__(512) void k_bsort(const unsigned int* __restrict__ pairs,
                                               const int* __restrict__ bstart,
                                               int* __restrict__ rowptr,
                                               int* __restrict__ stgt) {
    __shared__ int h[128];
    __shared__ int s[128];
    int b = blockIdx.x;
    int p0 = bstart[b], p1 = bstart[b + 1];
    int n0 = b << BSHIFT;
    int t = threadIdx.x;
    if (t < 128) h[t] = 0;
    __syncthreads();
    for (int i = p0 + t; i < p1; i += 512)
        atomicAdd(&h[pairs[i] >> 17], 1);
    __syncthreads();
    int v = (t < 128) ? h[t] : 0;
    if (t < 128) s[t] = v;
    __syncthreads();
    for (int d = 1; d < 128; d <<= 1) {
        int add = (t >= d && t < 128) ? s[t - d] : 0;
        __syncthreads();
        if (t < 128) s[t] += add;
        __syncthreads();
    }
    if (t < 128) {
        int pos = p0 + s[t] - v;
        int node = n0 + t;
        if (node < N_NODES) rowptr[node] = pos;
        h[t] = pos;
    }
    __syncthreads();
    for (int i = p0 + t; i < p1; i += 512) {
        unsigned int pr = pairs[i];
        int pos = atomicAdd(&h[pr >> 17], 1);
        stgt[pos] = (int)(pr & 0x1FFFF);
    }
}

// ------- k_agg11: agg10 with 32-edge chunks (halved per-chunk overhead) ---
// One wave per node. Per-wave LDS buf (SINGLE, 9216B):
//   [0..1023]   : atgt rows 32B/edge (32 edges) -> overwritten by fp32 w[e][h]
//   [1024..9215]: X[e][seg] 32 edges x 256B bf16 rows (linear)
// Staging: 9 gll16 (all 64 lanes distinct bytes). Weight phase: lane
// (e32=lane&31, q2=lane>>5) -> 4 exps for head-quad q2, in-place write,
// den4 per-lane. Compute: lane (seg, hp) as agg10, 32 edges/chunk.
// den epilogue: 5-step e-slot reduce + 4 cross-half shfls + scalar selects.
__global__ __launch_bounds__(256) void k_agg11(const int* __restrict__ rowptr,
                                               const int* __restrict__ stgt,
                                               const float* __restrict__ asrc,
                                               const float* __restrict__ atgt,
                                               const unsigned short* __restrict__ xb,
                                               unsigned short* __restrict__ aggout) {
    __shared__ char lds[4 * 9216];
    const int tid = threadIdx.x;
    const int wid = tid >> 6, lane = tid & 63;
    const int node = blockIdx.x * 4 + wid;
    if (node >= N_NODES) return;
    const int seg = lane & 15;
    const int hp = lane >> 4;
    const int e32 = lane & 31;        // weight-phase edge slot
    const int q2 = lane >> 5;         // weight-phase head quad
    const int base = rowptr[node], end = rowptr[node + 1];
    const int deg = end - base;
    const float4 asr4 = *reinterpret_cast<const float4*>(asrc + (size_t)node * 8 + q2 * 4);
    char* buf = lds + wid * 9216;

    float2 accA[4] = {}, accB[4] = {};
    float4 den4 = {0.f, 0.f, 0.f, 0.f};

    const int nch = (deg + 31) >> 5;

    auto eidx = [&](int c) {
        int i = base + c * 32 + e32;
        if (i >= end) i = end - 1;
        return i;
    };
    auto stage = [&](int t32) {
        int ta = __shfl(t32, lane >> 1);
        gll16(atgt + (size_t)ta * 8 + (lane & 1) * 4, buf);
#pragma unroll
        for (int p = 0; p < 8; ++p) {
            int te = __shfl(t32, p * 4 + (lane >> 4));
            gll16(xb + (size_t)te * 128 + seg * 8, buf + 1024 + p * 1024);
        }
    };

#define EDGE_STEP(E) { \
        uint4 xu = *reinterpret_cast<const uint4*>(Xb + (E) * 256 + seg * 16); \
        float2 w2 = *reinterpret_cast<const float2*>(buf + (E) * 32 + hp * 8); \
        _Pragma("unroll") \
        for (int i = 0; i < 4; ++i) { \
            unsigned int u = (&xu.x)[i]; \
            float2 xv; \
            xv.x = __builtin_bit_cast(float, u << 16); \
            xv.y = __builtin_bit_cast(float, u & 0xFFFF0000u); \
            asm("v_pk_fma_f32 %0, %1, %2, %0 op_sel:[0,0,0] op_sel_hi:[1,0,1]" \
                : "+v"(accA[i]) : "v"(xv), "v"(w2)); \
            asm("v_pk_fma_f32 %0, %1, %2, %0 op_sel:[0,1,0] op_sel_hi:[1,1,1]" \
                : "+v"(accB[i]) : "v"(xv), "v"(w2)); \
        } }

    if (nch > 0) {
        int t32 = stgt[eidx(0)];
        for (int c = 0; c < nch; ++c) {
            // drain prior chunk's LDS reads before gll overwrites the buffer
            asm volatile("s_waitcnt lgkmcnt(0)" ::: "memory");
            __builtin_amdgcn_sched_barrier(0);
            stage(t32);
            if (c + 1 < nch) t32 = stgt[eidx(c + 1)];
            asm volatile("s_waitcnt vmcnt(0)" ::: "memory");
            __builtin_amdgcn_sched_barrier(0);
            int cnt = deg - c * 32;
            if (cnt > 32) cnt = 32;
            // ---- weight phase: lane (e32, q2), in-place over buf[0..1023]
            {
                char* wp = buf + e32 * 32 + q2 * 16;
                float4 at4 = *reinterpret_cast<const float4*>(wp);
                float z0 = asr4.x + at4.x, z1 = asr4.y + at4.y;
                float z2 = asr4.z + at4.z, z3 = asr4.w + at4.w;
                float g0 = (z0 > 0.f) ? -z0 : -(ALPHA * z0);
                float g1 = (z1 > 0.f) ? -z1 : -(ALPHA * z1);
                float g2 = (z2 > 0.f) ? -z2 : -(ALPHA * z2);
                float g3 = (z3 > 0.f) ? -z3 : -(ALPHA * z3);
                bool ok = e32 < cnt;
                float4 w4;
                w4.x = ok ? __expf(g0) : 0.f;
                w4.y = ok ? __expf(g1) : 0.f;
                w4.z = ok ? __expf(g2) : 0.f;
                w4.w = ok ? __expf(g3) : 0.f;
                den4.x += w4.x; den4.y += w4.y; den4.z += w4.z; den4.w += w4.w;
                *reinterpret_cast<float4*>(wp) = w4;
            }
            asm volatile("s_waitcnt lgkmcnt(0)" ::: "memory");
            __builtin_amdgcn_sched_barrier(0);
            // ---- compute phase
            const char* Xb = buf + 1024;
            if (cnt == 32) {
#pragma unroll 4
                for (int e = 0; e < 32; ++e) EDGE_STEP(e)
            } else {
                for (int e = 0; e < cnt; ++e) EDGE_STEP(e)
            }
        }
    }
#undef EDGE_STEP

    // ---- den: reduce over the 32 e-slots (bits 0..4; q2 half preserved)
    for (int d = 1; d <= 16; d <<= 1) {
        den4.x += __shfl_xor(den4.x, d);
        den4.y += __shfl_xor(den4.y, d);
        den4.z += __shfl_xor(den4.z, d);
        den4.w += __shfl_xor(den4.w, d);
    }
    // heads 2hp, 2hp+1 live in half (hp>>1), components 2(hp&1), 2(hp&1)+1
    int srcl = (hp >> 1) << 5;
    float sx = __shfl(den4.x, srcl);
    float sy = __shfl(den4.y, srcl);
    float sz = __shfl(den4.z, srcl);
    float sw = __shfl(den4.w, srcl);
    float den0 = (hp & 1) ? sz : sx;
    float den1 = (hp & 1) ? sw : sy;
    float invA = 1.f / (den0 + 1e-10f);
    float invB = 1.f / (den1 + 1e-10f);
    ushort8 oA, oB;
#pragma unroll
    for (int i = 0; i < 4; ++i) {
        oA[2 * i] = f2b(accA[i].x * invA);
        oA[2 * i + 1] = f2b(accA[i].y * invA);
        oB[2 * i] = f2b(accB[i].x * invB);
        oB[2 * i + 1] = f2b(accB[i].y * invB);
    }
    unsigned short* op = aggout + (size_t)node * 1024 + (hp * 2) * 128 + seg * 8;
    *reinterpret_cast<ushort8*>(op) = oA;
    *reinterpret_cast<ushort8*>(op + 128) = oB;
}

// ------- final per-head GEMM: 128-row x 64-col tiles ----------------------
#define LDK2 136
__global__ __launch_bounds__(256) void k_gemm2(const unsigned short* __restrict__ agg,
                                               const unsigned short* __restrict__ Wt,
                                               float* __restrict__ out) {
    __shared__ unsigned short Al[128 * LDK2];
    __shared__ unsigned short Bl[64 * LDK2];
    const int tid = threadIdx.x;
    const int h = blockIdx.y;
    const int r0 = blockIdx.x * 128;
    for (int it = 0; it < 8; ++it) {
        int idx = tid + it * 256;           // 0..2047 ushort8
        int r = idx >> 4, k8 = (idx & 15) << 3;
        int gr = r0 + r;
        if (gr >= N_NODES) gr = N_NODES - 1;
        *reinterpret_cast<ushort8*>(&Al[r * LDK2 + k8]) =
            *reinterpret_cast<const ushort8*>(agg + (size_t)gr * 1024 + h * 128 + k8);
    }
    for (int it = 0; it < 4; ++it) {
        int idx = tid + it * 256;
        int f = idx >> 4, k8 = (idx & 15) << 3;
        *reinterpret_cast<ushort8*>(&Bl[f * LDK2 + k8]) =
            *reinterpret_cast<const ushort8*>(Wt + (size_t)(h * 64 + f) * 128 + k8);
    }
    __syncthreads();
    const int lane = tid & 63, w = tid >> 6;
    const int l15 = lane & 15, lq = lane >> 4;
    f32x4 acc[2][4] = {};
    for (int ks = 0; ks < 4; ++ks) {
        int koff = ks * 32 + lq * 8;
        bf16x8 af0 = *reinterpret_cast<const bf16x8*>(&Al[(w * 32 + l15) * LDK2 + koff]);
        bf16x8 af1 = *reinterpret_cast<const bf16x8*>(&Al[(w * 32 + 16 + l15) * LDK2 + koff]);
#pragma unroll
        for (int n = 0; n < 4; ++n) {
            bf16x8 bf_ = *reinterpret_cast<const bf16x8*>(&Bl[(n * 16 + l15) * LDK2 + koff]);
            acc[0][n] = __builtin_amdgcn_mfma_f32_16x16x32_bf16(af0, bf_, acc[0][n], 0, 0, 0);
            acc[1][n] = __builtin_amdgcn_mfma_f32_16x16x32_bf16(af1, bf_, acc[1][n], 0, 0, 0);
        }
    }
#pragma unroll
    for (int m = 0; m < 2; ++m)
#pragma unroll
        for (int n = 0; n < 4; ++n) {
            int col = h * 64 + n * 16 + l15;
            int rbase = r0 + w * 32 + m * 16 + lq * 4;
#pragma unroll
            for (int r2 = 0; r2 < 4; ++r2) {
                int rr = rbase + r2;
                if (rr < N_NODES) out[(size_t)rr * 512 + col] = acc[m][n][r2];
            }
        }
}

extern "C" void kernel_launch(void* const* d_in, const int* in_sizes, int n_in,
                              void* d_out, int out_size, void* d_ws, size_t ws_size,
                              hipStream_t stream) {
    const float* x = (const float*)d_in[0];
    const int* edges = (const int*)d_in[1];
    const float* W = (const float*)d_in[2];
    const float* a = (const float*)d_in[3];
    float* out = (float*)d_out;
    const int* src = edges;
    const int* tgt = edges + N_EDGES;

    char* ws = (char*)d_ws;
    size_t off = 0;
    auto alloc = [&](size_t bytes) -> void* {
        void* p = (void*)(ws + off);
        off += (bytes + 255) & ~(size_t)255;
        return p;
    };
    unsigned short* Wt = (unsigned short*)alloc((size_t)HEADS * OUT_F * IN_F * 2);
    float* uvT = (float*)alloc((size_t)IN_F * 16 * 4);
    unsigned short* xb = (unsigned short*)alloc((size_t)N_NODES * IN_F * 2);  // 25.6 MB
    float* asrc = (float*)alloc((size_t)N_NODES * 8 * 4);
    float* atgt = (float*)alloc((size_t)N_NODES * 8 * 4);
    int* bhist = (int*)alloc((size_t)NBUCK * 4);
    int* bstart = (int*)alloc((size_t)(NBUCK + 1) * 4);
    int* bcursor = (int*)alloc((size_t)NBUCK * 4);
    int* rowptr = (int*)alloc((size_t)(N_NODES + 1) * 4);
    unsigned int* pairs = (unsigned int*)alloc((size_t)N_EDGES * 4);  // 12.8 MB
    int* stgt = (int*)alloc((size_t)N_EDGES * 4);                     // 12.8 MB
    (void)ws_size; (void)n_in; (void)in_sizes; (void)out_size;

    k_prep<<<258, 256, 0, stream>>>(W, a, Wt, uvT, bhist);
    k_xadot<<<XADOT_BLKS + NPBLK, 256, 0, stream>>>(x, uvT, src, xb, asrc, atgt, bhist);
    k_bscan<<<1, 1024, 0, stream>>>(bhist, bstart, bcursor, rowptr);
    k_bscatter<<<NPBLK, 256, 0, stream>>>(src, tgt, bcursor, pairs);
    k_bsort<<<NBUCK, 512, 0, stream>>>(pairs, bstart, rowptr, stgt);
    k_agg11<<<25000, 256, 0, stream>>>(rowptr, stgt, asrc, atgt, xb,
                                       (unsigned short*)d_out);
    k_gemm2<<<dim3(782, 8), 256, 0, stream>>>((const unsigned short*)d_out, Wt, out);
}

// Round 18
// 455.223 us; speedup vs baseline: 1.0212x; 1.0212x over previous
//
#include <hip/hip_runtime.h>
#include <hip/hip_bf16.h>

#define N_NODES 100000
#define N_EDGES 3200000
#define IN_F 128
#define OUT_F 64
#define HEADS 8
#define ALPHA 0.2f

#define BSHIFT 7
#define NBUCK 782           // ceil(100000 / 128)
#define CHUNK 2048          // edges per partition block
#define NPBLK 1563          // ceil(N_EDGES / CHUNK)
#define XADOT_BLKS 1024     // node-work blocks in the fused xadot+bcount kernel

typedef __bf16 bf16x8 __attribute__((ext_vector_type(8)));
typedef float f32x4 __attribute__((ext_vector_type(4)));
typedef __attribute__((ext_vector_type(8))) unsigned short ushort8;

static __device__ __forceinline__ unsigned short f2b(float f) {
    __hip_bfloat16 h = __float2bfloat16(f);
    return __builtin_bit_cast(unsigned short, h);
}

static __device__ __forceinline__ void gll16(const void* g, void* l) {
    __builtin_amdgcn_global_load_lds(
        (const __attribute__((address_space(1))) void*)g,
        (__attribute__((address_space(3))) void*)l, 16, 0, 0);
}

// ------- merged prep: Wt transpose (blocks 0-255), uvT (block 256),
//         bhist zero (block 257) ------------------------------------------
__global__ __launch_bounds__(256) void k_prep(const float* __restrict__ W,
                                              const float* __restrict__ a,
                                              unsigned short* __restrict__ Wt,
                                              float* __restrict__ uvT,
                                              int* __restrict__ bhist) {
    int b = blockIdx.x, t = threadIdx.x;
    if (b < 256) {
        int idx = b * 256 + t;          // c*128 + k
        int k = idx & 127;
        int c = idx >> 7;
        int h = c >> 6;
        int f = c & 63;
        Wt[idx] = f2b(W[h * IN_F * OUT_F + k * OUT_F + f]);
    } else if (b == 256) {
#pragma unroll
        for (int j = 0; j < 4; ++j) {
            int t2 = t + j * 256;       // 0..1023 = h*128+k
            int h = t2 >> 7, k = t2 & 127;
            const float* Wrow = W + h * IN_F * OUT_F + k * OUT_F;
            const float* ah = a + h * 2 * OUT_F;
            float su = 0.f, sv = 0.f;
            for (int f = 0; f < OUT_F; ++f) {
                float wv = Wrow[f];
                su += wv * ah[f];
                sv += wv * ah[OUT_F + f];
            }
            uvT[k * 16 + h] = su;
            uvT[k * 16 + 8 + h] = sv;
        }
    } else {
        for (int i = t; i < NBUCK; i += 256) bhist[i] = 0;
    }
}

// ------- fused: xadot (blocks < XADOT_BLKS) + bucket histogram ------------
__global__ __launch_bounds__(256) void k_xadot(const float* __restrict__ x,
                                               const float* __restrict__ uvT,
                                               const int* __restrict__ src,
                                               unsigned short* __restrict__ xb,
                                               float* __restrict__ asrc,
                                               float* __restrict__ atgt,
                                               int* __restrict__ bhist) {
    const int b = blockIdx.x, t = threadIdx.x;
    if (b >= XADOT_BLKS) {
        __shared__ int h[NBUCK];
        for (int i = t; i < NBUCK; i += 256) h[i] = 0;
        __syncthreads();
        int cb = b - XADOT_BLKS;
        int i0 = cb * CHUNK;
        int iend = i0 + CHUNK;
        if (iend > N_EDGES) iend = N_EDGES;
        for (int i = i0 + t; i < iend; i += 256)
            atomicAdd(&h[src[i] >> BSHIFT], 1);
        __syncthreads();
        for (int i = t; i < NBUCK; i += 256)
            if (h[i]) atomicAdd(&bhist[i], h[i]);
        return;
    }
    const int lane = t & 63, wid = t >> 6;
    const int o = lane & 15, q = lane >> 4;
    float up[32];
#pragma unroll
    for (int j = 0; j < 32; ++j) up[j] = uvT[(q * 32 + j) * 16 + o];

    for (int n = b * 4 + wid; n < N_NODES; n += XADOT_BLKS * 4) {
        const float* xr = x + (size_t)n * 128;
        float2 xv2 = *reinterpret_cast<const float2*>(xr + 2 * lane);
        ushort2 pv = make_ushort2(f2b(xv2.x), f2b(xv2.y));
        *reinterpret_cast<ushort2*>(xb + (size_t)n * 128 + 2 * lane) = pv;
        float r = 0.f;
        const float4* xq = reinterpret_cast<const float4*>(xr + q * 32);
#pragma unroll
        for (int j = 0; j < 8; ++j) {
            float4 xv = xq[j];
            r = fmaf(xv.x, up[4 * j], r);
            r = fmaf(xv.y, up[4 * j + 1], r);
            r = fmaf(xv.z, up[4 * j + 2], r);
            r = fmaf(xv.w, up[4 * j + 3], r);
        }
        r += __shfl_xor(r, 16);
        r += __shfl_xor(r, 32);
        if (lane < 8) asrc[n * 8 + o] = r;
        else if (lane < 16) atgt[n * 8 + (o - 8)] = r;
    }
}

// ---------------- bucket scan (1 block); also init cursors ----------------
__global__ __launch_bounds__(1024) void k_bscan(const int* __restrict__ bhist,
                                                int* __restrict__ bstart,
                                                int* __restrict__ bcursor,
                                                int* __restrict__ rowptr) {
    __shared__ int s[1024];
    int t = threadIdx.x;
    int v = (t < NBUCK) ? bhist[t] : 0;
    s[t] = v;
    __syncthreads();
    for (int d = 1; d < 1024; d <<= 1) {
        int add = (t >= d) ? s[t - d] : 0;
        __syncthreads();
        s[t] += add;
        __syncthreads();
    }
    if (t < NBUCK) {
        int st = s[t] - v;
        bstart[t] = st;
        bcursor[t] = st;
    }
    if (t == 0) {
        bstart[NBUCK] = N_EDGES;
        rowptr[N_NODES] = N_EDGES;
    }
}

// ---------------- pass 1: partition edges into bucket regions -------------
__global__ __launch_bounds__(256) void k_bscatter(const int* __restrict__ src,
                                                  const int* __restrict__ tgt,
                                                  int* __restrict__ bcursor,
                                                  unsigned int* __restrict__ pairs) {
    __shared__ int h[NBUCK];
    __shared__ int rsv[NBUCK];
    for (int i = threadIdx.x; i < NBUCK; i += 256) h[i] = 0;
    __syncthreads();
    int i0 = blockIdx.x * CHUNK;
    int iend = i0 + CHUNK;
    if (iend > N_EDGES) iend = N_EDGES;
    for (int i = i0 + threadIdx.x; i < iend; i += 256)
        atomicAdd(&h[src[i] >> BSHIFT], 1);
    __syncthreads();
    for (int i = threadIdx.x; i < NBUCK; i += 256) {
        int c = h[i];
        rsv[i] = c ? atomicAdd(&bcursor[i], c) : 0;
        h[i] = 0;
    }
    __syncthreads();
    for (int i = i0 + threadIdx.x; i < iend; i += 256) {
        int s = src[i];
        int b = s >> BSHIFT;
        int p = rsv[b] + atomicAdd(&h[b], 1);
        pairs[p] = ((unsigned)(s & 127) << 17) | (unsigned)tgt[i];
    }
}

// ---------------- pass 2: in-bucket counting sort -> stgt + rowptr --------
__global__ __launch_bounds__(512) void k_bsort(const unsigned int* __restrict__ pairs,
                                               const int* __restrict__ bstart,
                                               int* __restrict__ rowptr,
                                               int* __restrict__ stgt) {
    __shared__ int h[128];
    __shared__ int s[128];
    int b = blockIdx.x;
    int p0 = bstart[b], p1 = bstart[b + 1];
    int n0 = b << BSHIFT;
    int t = threadIdx.x;
    if (t < 128) h[t] = 0;
    __syncthreads();
    for (int i = p0 + t; i < p1; i += 512)
        atomicAdd(&h[pairs[i] >> 17], 1);
    __syncthreads();
    int v = (t < 128) ? h[t] : 0;
    if (t < 128) s[t] = v;
    __syncthreads();
    for (int d = 1; d < 128; d <<= 1) {
        int add = (t >= d && t < 128) ? s[t - d] : 0;
        __syncthreads();
        if (t < 128) s[t] += add;
        __syncthreads();
    }
    if (t < 128) {
        int pos = p0 + s[t] - v;
        int node = n0 + t;
        if (node < N_NODES) rowptr[node] = pos;
        h[t] = pos;
    }
    __syncthreads();
    for (int i = p0 + t; i < p1; i += 512) {
        unsigned int pr = pairs[i];
        int pos = atomicAdd(&h[pr >> 17], 1);
        stgt[pos] = (int)(pr & 0x1FFFF);
    }
}

// ------- k_agg10: single-buffer, op_sel pk_fma (round-15 exact) -----------
// One wave per node. Chunk = 16 edges. Per-wave LDS buf (SINGLE, 5120B):
//   [0..1023]   : atgt rows (32B/edge) -> overwritten in-place with weights
//   [1024..5119]: X[e][seg] 16 edges x 256B bf16 rows
// 20KB/block -> 8 blocks/CU; TLP hides the per-chunk vmcnt(0) stall.
__global__ __launch_bounds__(256) void k_agg10(const int* __restrict__ rowptr,
                                               const int* __restrict__ stgt,
                                               const float* __restrict__ asrc,
                                               const float* __restrict__ atgt,
                                               const unsigned short* __restrict__ xb,
                                               unsigned short* __restrict__ aggout) {
    __shared__ char lds[4 * 5120];
    const int tid = threadIdx.x;
    const int wid = tid >> 6, lane = tid & 63;
    const int node = blockIdx.x * 4 + wid;
    if (node >= N_NODES) return;
    const int seg = lane & 15;
    const int hp = lane >> 4;
    const int base = rowptr[node], end = rowptr[node + 1];
    const float2 asr = *reinterpret_cast<const float2*>(asrc + (size_t)node * 8 + hp * 2);
    char* buf = lds + wid * 5120;

    float2 accA[4] = {}, accB[4] = {};
    float den0 = 0.f, den1 = 0.f;

    const int deg = end - base;
    const int nch = (deg + 15) >> 4;

    auto eidx = [&](int c) {
        int i = base + c * 16 + seg;
        if (i >= end) i = end - 1;
        return i;
    };
    auto stage = [&](int t16) {
        int te_a = __shfl(t16, (lane & 31) >> 1);
        gll16(atgt + (size_t)te_a * 8 + (lane & 1) * 4, buf);
#pragma unroll
        for (int p = 0; p < 4; ++p) {
            int te = __shfl(t16, p * 4 + hp);
            gll16(xb + (size_t)te * 128 + seg * 8, buf + 1024 + p * 1024);
        }
    };

#define EDGE_STEP(E) { \
        uint4 xu = *reinterpret_cast<const uint4*>(Xb + (E) * 256 + seg * 16); \
        float2 w2 = *reinterpret_cast<const float2*>(buf + (E) * 32 + hp * 8); \
        _Pragma("unroll") \
        for (int i = 0; i < 4; ++i) { \
            unsigned int u = (&xu.x)[i]; \
            float2 xv; \
            xv.x = __builtin_bit_cast(float, u << 16); \
            xv.y = __builtin_bit_cast(float, u & 0xFFFF0000u); \
            asm("v_pk_fma_f32 %0, %1, %2, %0 op_sel:[0,0,0] op_sel_hi:[1,0,1]" \
                : "+v"(accA[i]) : "v"(xv), "v"(w2)); \
            asm("v_pk_fma_f32 %0, %1, %2, %0 op_sel:[0,1,0] op_sel_hi:[1,1,1]" \
                : "+v"(accB[i]) : "v"(xv), "v"(w2)); \
        } }

    if (nch > 0) {
        int t16 = stgt[eidx(0)];
        for (int c = 0; c < nch; ++c) {
            asm volatile("s_waitcnt lgkmcnt(0)" ::: "memory");
            __builtin_amdgcn_sched_barrier(0);
            stage(t16);
            if (c + 1 < nch) t16 = stgt[eidx(c + 1)];
            asm volatile("s_waitcnt vmcnt(0)" ::: "memory");
            __builtin_amdgcn_sched_barrier(0);
            int c0 = base + c * 16;
            int cnt = end - c0;
            if (cnt > 16) cnt = 16;
            {
                float2 at2 = *reinterpret_cast<const float2*>(buf + seg * 32 + hp * 8);
                float z0 = asr.x + at2.x, z1 = asr.y + at2.y;
                float e0 = (z0 > 0.f) ? -z0 : -(ALPHA * z0);
                float e1 = (z1 > 0.f) ? -z1 : -(ALPHA * z1);
                bool ok = seg < cnt;
                float w0 = ok ? __expf(e0) : 0.f;
                float w1 = ok ? __expf(e1) : 0.f;
                den0 += w0;
                den1 += w1;
                float2 wout = {w0, w1};
                *reinterpret_cast<float2*>(buf + seg * 32 + hp * 8) = wout;
            }
            asm volatile("s_waitcnt lgkmcnt(0)" ::: "memory");
            __builtin_amdgcn_sched_barrier(0);
            const char* Xb = buf + 1024;
            if (cnt == 16) {
#pragma unroll 4
                for (int e = 0; e < 16; ++e) EDGE_STEP(e)
            } else {
                for (int e = 0; e < cnt; ++e) EDGE_STEP(e)
            }
        }
    }
#undef EDGE_STEP

    for (int d = 1; d <= 8; d <<= 1) {
        den0 += __shfl_xor(den0, d);
        den1 += __shfl_xor(den1, d);
    }
    float invA = 1.f / (den0 + 1e-10f);
    float invB = 1.f / (den1 + 1e-10f);
    ushort8 oA, oB;
#pragma unroll
    for (int i = 0; i < 4; ++i) {
        oA[2 * i] = f2b(accA[i].x * invA);
        oA[2 * i + 1] = f2b(accA[i].y * invA);
        oB[2 * i] = f2b(accB[i].x * invB);
        oB[2 * i + 1] = f2b(accB[i].y * invB);
    }
    unsigned short* op = aggout + (size_t)node * 1024 + (hp * 2) * 128 + seg * 8;
    *reinterpret_cast<ushort8*>(op) = oA;
    *reinterpret_cast<ushort8*>(op + 128) = oB;
}

// ------- final per-head GEMM: 128-row x 64-col tiles (round-17 keep) ------
#define LDK2 136
__global__ __launch_bounds__(256) void k_gemm2(const unsigned short* __restrict__ agg,
                                               const unsigned short* __restrict__ Wt,
                                               float* __restrict__ out) {
    __shared__ unsigned short Al[128 * LDK2];
    __shared__ unsigned short Bl[64 * LDK2];
    const int tid = threadIdx.x;
    const int h = blockIdx.y;
    const int r0 = blockIdx.x * 128;
    for (int it = 0; it < 8; ++it) {
        int idx = tid + it * 256;           // 0..2047 ushort8
        int r = idx >> 4, k8 = (idx & 15) << 3;
        int gr = r0 + r;
        if (gr >= N_NODES) gr = N_NODES - 1;
        *reinterpret_cast<ushort8*>(&Al[r * LDK2 + k8]) =
            *reinterpret_cast<const ushort8*>(agg + (size_t)gr * 1024 + h * 128 + k8);
    }
    for (int it = 0; it < 4; ++it) {
        int idx = tid + it * 256;
        int f = idx >> 4, k8 = (idx & 15) << 3;
        *reinterpret_cast<ushort8*>(&Bl[f * LDK2 + k8]) =
            *reinterpret_cast<const ushort8*>(Wt + (size_t)(h * 64 + f) * 128 + k8);
    }
    __syncthreads();
    const int lane = tid & 63, w = tid >> 6;
    const int l15 = lane & 15, lq = lane >> 4;
    f32x4 acc[2][4] = {};
    for (int ks = 0; ks < 4; ++ks) {
        int koff = ks * 32 + lq * 8;
        bf16x8 af0 = *reinterpret_cast<const bf16x8*>(&Al[(w * 32 + l15) * LDK2 + koff]);
        bf16x8 af1 = *reinterpret_cast<const bf16x8*>(&Al[(w * 32 + 16 + l15) * LDK2 + koff]);
#pragma unroll
        for (int n = 0; n < 4; ++n) {
            bf16x8 bf_ = *reinterpret_cast<const bf16x8*>(&Bl[(n * 16 + l15) * LDK2 + koff]);
            acc[0][n] = __builtin_amdgcn_mfma_f32_16x16x32_bf16(af0, bf_, acc[0][n], 0, 0, 0);
            acc[1][n] = __builtin_amdgcn_mfma_f32_16x16x32_bf16(af1, bf_, acc[1][n], 0, 0, 0);
        }
    }
#pragma unroll
    for (int m = 0; m < 2; ++m)
#pragma unroll
        for (int n = 0; n < 4; ++n) {
            int col = h * 64 + n * 16 + l15;
            int rbase = r0 + w * 32 + m * 16 + lq * 4;
#pragma unroll
            for (int r2 = 0; r2 < 4; ++r2) {
                int rr = rbase + r2;
                if (rr < N_NODES) out[(size_t)rr * 512 + col] = acc[m][n][r2];
            }
        }
}

extern "C" void kernel_launch(void* const* d_in, const int* in_sizes, int n_in,
                              void* d_out, int out_size, void* d_ws, size_t ws_size,
                              hipStream_t stream) {
    const float* x = (const float*)d_in[0];
    const int* edges = (const int*)d_in[1];
    const float* W = (const float*)d_in[2];
    const float* a = (const float*)d_in[3];
    float* out = (float*)d_out;
    const int* src = edges;
    const int* tgt = edges + N_EDGES;

    char* ws = (char*)d_ws;
    size_t off = 0;
    auto alloc = [&](size_t bytes) -> void* {
        void* p = (void*)(ws + off);
        off += (bytes + 255) & ~(size_t)255;
        return p;
    };
    unsigned short* Wt = (unsigned short*)alloc((size_t)HEADS * OUT_F * IN_F * 2);
    float* uvT = (float*)alloc((size_t)IN_F * 16 * 4);
    unsigned short* xb = (unsigned short*)alloc((size_t)N_NODES * IN_F * 2);  // 25.6 MB
    float* asrc = (float*)alloc((size_t)N_NODES * 8 * 4);
    float* atgt = (float*)alloc((size_t)N_NODES * 8 * 4);
    int* bhist = (int*)alloc((size_t)NBUCK * 4);
    int* bstart = (int*)alloc((size_t)(NBUCK + 1) * 4);
    int* bcursor = (int*)alloc((size_t)NBUCK * 4);
    int* rowptr = (int*)alloc((size_t)(N_NODES + 1) * 4);
    unsigned int* pairs = (unsigned int*)alloc((size_t)N_EDGES * 4);  // 12.8 MB
    int* stgt = (int*)alloc((size_t)N_EDGES * 4);                     // 12.8 MB
    (void)ws_size; (void)n_in; (void)in_sizes; (void)out_size;

    k_prep<<<258, 256, 0, stream>>>(W, a, Wt, uvT, bhist);
    k_xadot<<<XADOT_BLKS + NPBLK, 256, 0, stream>>>(x, uvT, src, xb, asrc, atgt, bhist);
    k_bscan<<<1, 1024, 0, stream>>>(bhist, bstart, bcursor, rowptr);
    k_bscatter<<<NPBLK, 256, 0, stream>>>(src, tgt, bcursor, pairs);
    k_bsort<<<NBUCK, 512, 0, stream>>>(pairs, bstart, rowptr, stgt);
    k_agg10<<<25000, 256, 0, stream>>>(rowptr, stgt, asrc, atgt, xb,
                                       (unsigned short*)d_out);
    k_gemm2<<<dim3(782, 8), 256, 0, stream>>>((const unsigned short*)d_out, Wt, out);
}